// Round 10
// baseline (169.222 us; speedup 1.0000x reference)
//
#include <hip/hip_runtime.h>

typedef unsigned short u16;
typedef short bfrag __attribute__((ext_vector_type(8)));   // 8 x bf16 (4 VGPRs)
typedef float facc  __attribute__((ext_vector_type(4)));   // 4 x f32
typedef float f16x  __attribute__((ext_vector_type(16)));  // 16 x f32 (32x32 acc)

__device__ __forceinline__ u16 f2bf(float f){
  union { float f; unsigned u; } v; v.f = f;
  unsigned r = v.u + 0x7fffu + ((v.u >> 16) & 1u);
  return (u16)(r >> 16);
}

__device__ __forceinline__ unsigned cvt_pk_bf16(float lo, float hi){
  unsigned d;
  asm("v_cvt_pk_bf16_f32 %0, %1, %2" : "=v"(d) : "v"(lo), "v"(hi));
  return d;
}

__device__ __forceinline__ void gl_lds16(const void* g, void* l){
  __builtin_amdgcn_global_load_lds(
      (const __attribute__((address_space(1))) unsigned int*)g,
      (__attribute__((address_space(3))) unsigned int*)l,
      16, 0, 0);
}

// ---------------- fp32 -> bf16 conversion ----------------
__global__ __launch_bounds__(256) void cvt_kernel(const float* __restrict__ src,
                                                  u16* __restrict__ dst, int n){
  int i = (blockIdx.x * 256 + threadIdx.x) * 4;
  if (i < n){
    float4 f = *(const float4*)(src + i);
    ushort4 o;
    o.x = f2bf(f.x); o.y = f2bf(f.y); o.z = f2bf(f.z); o.w = f2bf(f.w);
    *(ushort4*)(dst + i) = o;
  }
}

// ---------------- bf16 GEMM: C[m,n] = sum_k A[m,k]*B[n,k] + bias[n] ----------------
__device__ __forceinline__ void stage_tile(const u16* __restrict__ G, u16* lds,
                                           int row0, int k0, int K, int tid){
  #pragma unroll
  for (int c = 0; c < 2; ++c){
    int e = c * 2048 + tid * 8;
    int row = e >> 5, col = e & 31;
    gl_lds16(G + (size_t)(row0 + row) * K + k0 + col, lds + c * 2048 + (tid >> 6) * 512);
  }
}

template<int EPI>
__global__ __launch_bounds__(256) void gemm_bt(
    const u16* __restrict__ A, const u16* __restrict__ B,
    const float* __restrict__ bias, float* __restrict__ Cf,
    u16* __restrict__ qkv, int M, int N, int K)
{
  __shared__ u16 Ash[2][4096];
  __shared__ u16 Bsh[2][4096];
  const int tid = threadIdx.x, lane = tid & 63;
  const int w = tid >> 6, wm = w >> 1, wn = w & 1;
  const int cl = lane & 15, g8 = (lane >> 4) * 8;
  const int n0 = blockIdx.x * 128, m0 = blockIdx.y * 128;

  facc acc[4][4];
  #pragma unroll
  for (int mi = 0; mi < 4; ++mi)
    #pragma unroll
    for (int ni = 0; ni < 4; ++ni)
      acc[mi][ni] = (facc){0.f, 0.f, 0.f, 0.f};

  const int NT = K >> 5;
  stage_tile(A, Ash[0], m0, 0, K, tid);
  stage_tile(B, Bsh[0], n0, 0, K, tid);
  __syncthreads();
  int cur = 0;
  for (int kt = 0; kt < NT; ++kt){
    if (kt + 1 < NT){
      stage_tile(A, Ash[cur ^ 1], m0, (kt + 1) << 5, K, tid);
      stage_tile(B, Bsh[cur ^ 1], n0, (kt + 1) << 5, K, tid);
    }
    const u16* As = Ash[cur]; const u16* Bs = Bsh[cur];
    bfrag af[4], bfr[4];
    #pragma unroll
    for (int mi = 0; mi < 4; ++mi)
      af[mi] = *(const bfrag*)&As[(wm * 64 + mi * 16 + cl) * 32 + g8];
    #pragma unroll
    for (int ni = 0; ni < 4; ++ni)
      bfr[ni] = *(const bfrag*)&Bs[(wn * 64 + ni * 16 + cl) * 32 + g8];
    #pragma unroll
    for (int mi = 0; mi < 4; ++mi)
      #pragma unroll
      for (int ni = 0; ni < 4; ++ni)
        acc[mi][ni] = __builtin_amdgcn_mfma_f32_16x16x32_bf16(af[mi], bfr[ni], acc[mi][ni], 0, 0, 0);
    __syncthreads();
    cur ^= 1;
  }

  const int r0 = (lane >> 4) * 4;
  #pragma unroll
  for (int mi = 0; mi < 4; ++mi){
    const int mbase = m0 + wm * 64 + mi * 16 + r0;
    #pragma unroll
    for (int ni = 0; ni < 4; ++ni){
      const int n = n0 + wn * 64 + ni * 16 + cl;
      const float bv = bias[n];
      #pragma unroll
      for (int j = 0; j < 4; ++j){
        float v = acc[mi][ni][j] + bv;
        const int mm = mbase + j;
        if (EPI == 0){
          Cf[(size_t)mm * N + n] = v;
        } else {
          const int part = n >> 10, rest = n & 1023;
          const int h = rest >> 6, d = rest & 63;
          const int bb = mm >> 11, s = mm & 2047;
          // fold 1/sqrt(dh)=1/8 AND log2(e) into q so attention uses exp2 directly
          if (part == 0) v *= 0.18033688011112042f;
          if (part < 2){
            qkv[(size_t)part * 4194304 + (size_t)((bb * 16 + h) * 2048 + s) * 64 + d] = f2bf(v);
          } else {
            // v stored TRANSPOSED: VT[bh][d][s] so attention reads contiguous j-runs
            qkv[(size_t)2 * 4194304 + (size_t)((bb * 16 + h) * 64 + d) * 2048 + s] = f2bf(v);
          }
        }
      }
    }
  }
}

// ---------------- swapped-role causal flash attention (LDS-free) ----------------
// out[i] = sum_{j<=i} softmax_j( Kproj[i] . Qproj[j]*log2e/8 ) * V[j], exp2 domain.
// One wave per 32 output rows. All operands streamed from global/L2:
//   K A-frags: row-major contiguous; V B-frags: contiguous thanks to VT layout.
// S^T = mfma(K, Q): lane (hi,il) holds S[j=qj(r)][i=il]; P in registers (T12).
__global__ __launch_bounds__(64) void attn_kernel(
    const u16* __restrict__ qarr, const u16* __restrict__ karr,
    const u16* __restrict__ vtarr, u16* __restrict__ aout,
    const int* __restrict__ cmask)
{
  const int lane = threadIdx.x;
  const int il = lane & 31, hi = lane >> 5;
  const int bh = blockIdx.x;                    // bh -> XCD (K/Q/VT L2-resident)
  const int jw = 63 - (int)blockIdx.y;          // 32-row stripe, heavy first
  const int iw = jw * 32;
  const u16* Qh  = karr  + (size_t)bh * 131072; // output rows come from k-proj
  const u16* Kh  = qarr  + (size_t)bh * 131072; // keys are q-proj (pre-scaled)
  const u16* VTh = vtarr + (size_t)bh * 131072; // V transposed [d][s]
  const bool do_mask = (cmask[0] != 0);

  // persistent Q B-frags: bq[kt] holds Q[iw+il][kt*16 + 8*hi + e]
  bfrag bq[4];
  #pragma unroll
  for (int kt = 0; kt < 4; ++kt)
    bq[kt] = *(const bfrag*)(Qh + (size_t)(iw + il) * 64 + kt * 16 + hi * 8);

  f16x o0, o1, lacc;
  #pragma unroll
  for (int r = 0; r < 16; ++r){ o0[r] = 0.f; o1[r] = 0.f; lacc[r] = 0.f; }
  float m_s = -1e30f;

  bfrag ones;
  #pragma unroll
  for (int e = 0; e < 8; ++e) ones[e] = (short)0x3F80;  // bf16 1.0

  const int my_diag = do_mask ? (jw >> 1) : 31; // last 64-wide j-tile
  const int dsub    = jw & 1;                   // diagonal 32-subtile within it

  for (int jt = 0; jt <= my_diag; ++jt){
    const bool diag = do_mask && (jt == my_diag);
    const int nsub = diag ? (dsub + 1) : 2;     // wave-uniform
    const u16* Kt = Kh + (size_t)jt * 4096;

    // S^T = K . Q^T  (up to two 32x32 j-subtiles; K frags straight from L2)
    f16x s[2];
    #pragma unroll
    for (int sub = 0; sub < 2; ++sub)
      #pragma unroll
      for (int r = 0; r < 16; ++r) s[sub][r] = 0.f;
    __builtin_amdgcn_s_setprio(1);
    #pragma unroll
    for (int kt = 0; kt < 4; ++kt){
      #pragma unroll
      for (int sub = 0; sub < 2; ++sub){
        if (sub < nsub){
          bfrag ak = *(const bfrag*)(Kt + (size_t)(sub * 32 + il) * 64 + kt * 16 + hi * 8);
          s[sub] = __builtin_amdgcn_mfma_f32_32x32x16_bf16(ak, bq[kt], s[sub], 0, 0, 0);
        }
      }
    }
    __builtin_amdgcn_s_setprio(0);

    if (diag){                                  // mask j > i within the 32x32 diagonal
      #pragma unroll
      for (int r = 0; r < 16; ++r){
        const int qj = (r & 3) + 8 * (r >> 2) + 4 * hi;
        if (qj > il) s[dsub][r] = -1e30f;
      }
    }

    // row max: pairwise tree + 1 permlane32_swap
    float tmax = -1e30f;
    #pragma unroll
    for (int sub = 0; sub < 2; ++sub){
      if (sub < nsub){
        float a[8];
        #pragma unroll
        for (int e = 0; e < 8; ++e) a[e] = fmaxf(s[sub][e], s[sub][e + 8]);
        #pragma unroll
        for (int e = 0; e < 4; ++e) a[e] = fmaxf(a[e], a[e + 4]);
        a[0] = fmaxf(fmaxf(a[0], a[2]), fmaxf(a[1], a[3]));
        tmax = fmaxf(tmax, a[0]);
      }
    }
    {
      auto tt = __builtin_amdgcn_permlane32_swap(__float_as_uint(tmax),
                                                 __float_as_uint(tmax), false, false);
      tmax = fmaxf(__uint_as_float(tt[0]), __uint_as_float(tt[1]));
    }
    if (__any(tmax - m_s > 8.0f)){              // defer-max (THR=8)
      const float nm = fmaxf(m_s, tmax);
      const float sc = __builtin_amdgcn_exp2f(m_s - nm);
      m_s = nm;
      #pragma unroll
      for (int r = 0; r < 16; ++r){
        const float scb = __shfl(sc, (r & 3) + 8 * (r >> 2) + 4 * hi, 64);
        lacc[r] *= scb; o0[r] *= scb; o1[r] *= scb;
      }
    }

    // P = exp2(S - m); T12 cvt_pk + permlane32_swap -> PV A-frags; l via ones-MFMA
    #pragma unroll
    for (int sub = 0; sub < 2; ++sub){
      if (sub < nsub){
        #pragma unroll
        for (int r = 0; r < 16; ++r) s[sub][r] = __builtin_amdgcn_exp2f(s[sub][r] - m_s);
        #pragma unroll
        for (int half = 0; half < 2; ++half){
          const int q0 = 8 * half;
          unsigned a0 = cvt_pk_bf16(s[sub][q0],     s[sub][q0 + 1]);
          unsigned a1 = cvt_pk_bf16(s[sub][q0 + 2], s[sub][q0 + 3]);
          unsigned b0 = cvt_pk_bf16(s[sub][q0 + 4], s[sub][q0 + 5]);
          unsigned b1 = cvt_pk_bf16(s[sub][q0 + 6], s[sub][q0 + 7]);
          auto r0p = __builtin_amdgcn_permlane32_swap(a0, b0, false, false);
          auto r1p = __builtin_amdgcn_permlane32_swap(a1, b1, false, false);
          union { bfrag f; unsigned u[4]; } pa;
          pa.u[0] = r0p[0]; pa.u[1] = r1p[0]; pa.u[2] = r0p[1]; pa.u[3] = r1p[1];

          const int jcol = jt * 64 + sub * 32 + half * 16 + hi * 8;
          bfrag v0 = *(const bfrag*)(VTh + (size_t)il * 2048 + jcol);
          bfrag v1 = *(const bfrag*)(VTh + (size_t)(32 + il) * 2048 + jcol);
          lacc = __builtin_amdgcn_mfma_f32_32x32x16_bf16(pa.f, ones, lacc, 0, 0, 0);
          __builtin_amdgcn_s_setprio(1);
          o0 = __builtin_amdgcn_mfma_f32_32x32x16_bf16(pa.f, v0, o0, 0, 0, 0);
          o1 = __builtin_amdgcn_mfma_f32_32x32x16_bf16(pa.f, v1, o1, 0, 0, 0);
          __builtin_amdgcn_s_setprio(0);
        }
      }
    }
  }

  // epilogue: o0[r]=O[iw+qj(r)][il], o1 -> d=32+il; lacc[r] = l of the same row
  const int bb = bh >> 4, h = bh & 15;
  #pragma unroll
  for (int r = 0; r < 16; ++r){
    const float inv = 1.0f / lacc[r];
    const int row = iw + (r & 3) + 8 * (r >> 2) + 4 * hi;
    u16* dst = aout + (size_t)(bb * 2048 + row) * 1024 + h * 64 + il;
    dst[0]  = f2bf(o0[r] * inv);
    dst[32] = f2bf(o1[r] * inv);
  }
}

// ---------------- launch ----------------
extern "C" void kernel_launch(void* const* d_in, const int* in_sizes, int n_in,
                              void* d_out, int out_size, void* d_ws, size_t ws_size,
                              hipStream_t stream)
{
  const float* x     = (const float*)d_in[0];
  const float* w_in  = (const float*)d_in[1];
  const float* b_in  = (const float*)d_in[2];
  const float* w_out = (const float*)d_in[3];
  const float* b_out = (const float*)d_in[4];
  const int*   cmask = (const int*)d_in[5];

  u16* ws     = (u16*)d_ws;
  u16* xb     = ws;                 // 4096x1024
  u16* winb   = ws + 4194304;       // 3072x1024
  u16* woutb  = ws + 7340032;       // 1024x1024
  u16* qs     = ws + 8388608;       // q,k: [2,16,2048,64]; VT: [2,16,64,2048]
  u16* attn_o = ws + 20971520;      // 4096x1024

  cvt_kernel<<<4096, 256, 0, stream>>>(x, xb, 4194304);
  cvt_kernel<<<3072, 256, 0, stream>>>(w_in, winb, 3145728);
  cvt_kernel<<<1024, 256, 0, stream>>>(w_out, woutb, 1048576);

  gemm_bt<1><<<dim3(24, 32), 256, 0, stream>>>(xb, winb, b_in, nullptr, qs, 4096, 3072, 1024);

  attn_kernel<<<dim3(32, 64), 64, 0, stream>>>(qs, qs + 4194304, qs + 8388608, attn_o, cmask);

  gemm_bt<0><<<dim3(8, 32), 256, 0, stream>>>(attn_o, woutb, b_out, (float*)d_out, nullptr,
                                              4096, 1024, 1024);
}

// Round 11
// 155.180 us; speedup vs baseline: 1.0905x; 1.0905x over previous
//
#include <hip/hip_runtime.h>

typedef unsigned short u16;
typedef short bfrag __attribute__((ext_vector_type(8)));   // 8 x bf16 (4 VGPRs)
typedef float facc  __attribute__((ext_vector_type(4)));   // 4 x f32
typedef float f16x  __attribute__((ext_vector_type(16)));  // 16 x f32 (32x32 acc)

__device__ __forceinline__ u16 f2bf(float f){
  union { float f; unsigned u; } v; v.f = f;
  unsigned r = v.u + 0x7fffu + ((v.u >> 16) & 1u);
  return (u16)(r >> 16);
}

__device__ __forceinline__ unsigned cvt_pk_bf16(float lo, float hi){
  unsigned d;
  asm("v_cvt_pk_bf16_f32 %0, %1, %2" : "=v"(d) : "v"(lo), "v"(hi));
  return d;
}

__device__ __forceinline__ void gl_lds16(const void* g, void* l){
  __builtin_amdgcn_global_load_lds(
      (const __attribute__((address_space(1))) unsigned int*)g,
      (__attribute__((address_space(3))) unsigned int*)l,
      16, 0, 0);
}

// ---------------- fp32 -> bf16 conversion ----------------
__global__ __launch_bounds__(256) void cvt_kernel(const float* __restrict__ src,
                                                  u16* __restrict__ dst, int n){
  int i = (blockIdx.x * 256 + threadIdx.x) * 4;
  if (i < n){
    float4 f = *(const float4*)(src + i);
    ushort4 o;
    o.x = f2bf(f.x); o.y = f2bf(f.y); o.z = f2bf(f.z); o.w = f2bf(f.w);
    *(ushort4*)(dst + i) = o;
  }
}

// ---------------- bf16 GEMM: C[m,n] = sum_k A[m,k]*B[n,k] + bias[n] ----------------
__device__ __forceinline__ void stage_tile(const u16* __restrict__ G, u16* lds,
                                           int row0, int k0, int K, int tid){
  #pragma unroll
  for (int c = 0; c < 2; ++c){
    int e = c * 2048 + tid * 8;
    int row = e >> 5, col = e & 31;
    gl_lds16(G + (size_t)(row0 + row) * K + k0 + col, lds + c * 2048 + (tid >> 6) * 512);
  }
}

template<int EPI>
__global__ __launch_bounds__(256) void gemm_bt(
    const u16* __restrict__ A, const u16* __restrict__ B,
    const float* __restrict__ bias, float* __restrict__ Cf,
    u16* __restrict__ qkv, int M, int N, int K)
{
  __shared__ u16 Ash[2][4096];
  __shared__ u16 Bsh[2][4096];
  const int tid = threadIdx.x, lane = tid & 63;
  const int w = tid >> 6, wm = w >> 1, wn = w & 1;
  const int cl = lane & 15, g8 = (lane >> 4) * 8;
  const int n0 = blockIdx.x * 128, m0 = blockIdx.y * 128;

  facc acc[4][4];
  #pragma unroll
  for (int mi = 0; mi < 4; ++mi)
    #pragma unroll
    for (int ni = 0; ni < 4; ++ni)
      acc[mi][ni] = (facc){0.f, 0.f, 0.f, 0.f};

  const int NT = K >> 5;
  stage_tile(A, Ash[0], m0, 0, K, tid);
  stage_tile(B, Bsh[0], n0, 0, K, tid);
  __syncthreads();
  int cur = 0;
  for (int kt = 0; kt < NT; ++kt){
    if (kt + 1 < NT){
      stage_tile(A, Ash[cur ^ 1], m0, (kt + 1) << 5, K, tid);
      stage_tile(B, Bsh[cur ^ 1], n0, (kt + 1) << 5, K, tid);
    }
    const u16* As = Ash[cur]; const u16* Bs = Bsh[cur];
    bfrag af[4], bfr[4];
    #pragma unroll
    for (int mi = 0; mi < 4; ++mi)
      af[mi] = *(const bfrag*)&As[(wm * 64 + mi * 16 + cl) * 32 + g8];
    #pragma unroll
    for (int ni = 0; ni < 4; ++ni)
      bfr[ni] = *(const bfrag*)&Bs[(wn * 64 + ni * 16 + cl) * 32 + g8];
    #pragma unroll
    for (int mi = 0; mi < 4; ++mi)
      #pragma unroll
      for (int ni = 0; ni < 4; ++ni)
        acc[mi][ni] = __builtin_amdgcn_mfma_f32_16x16x32_bf16(af[mi], bfr[ni], acc[mi][ni], 0, 0, 0);
    __syncthreads();
    cur ^= 1;
  }

  const int r0 = (lane >> 4) * 4;
  #pragma unroll
  for (int mi = 0; mi < 4; ++mi){
    const int mbase = m0 + wm * 64 + mi * 16 + r0;
    #pragma unroll
    for (int ni = 0; ni < 4; ++ni){
      const int n = n0 + wn * 64 + ni * 16 + cl;
      const float bv = bias[n];
      #pragma unroll
      for (int j = 0; j < 4; ++j){
        float v = acc[mi][ni][j] + bv;
        const int mm = mbase + j;
        if (EPI == 0){
          Cf[(size_t)mm * N + n] = v;
        } else {
          const int part = n >> 10, rest = n & 1023;
          const int h = rest >> 6, d = rest & 63;
          const int bb = mm >> 11, s = mm & 2047;
          // fold 1/sqrt(dh)=1/8 AND log2(e) into q so attention uses exp2 directly
          if (part == 0) v *= 0.18033688011112042f;
          if (part < 2){
            qkv[(size_t)part * 4194304 + (size_t)((bb * 16 + h) * 2048 + s) * 64 + d] = f2bf(v);
          } else {
            // v stored TRANSPOSED: VT[bh][d][s] so attention reads contiguous j-runs
            qkv[(size_t)2 * 4194304 + (size_t)((bb * 16 + h) * 64 + d) * 2048 + s] = f2bf(v);
          }
        }
      }
    }
  }
}

// ---------------- swapped-role causal flash attention (LDS-free core) ----------
// out[i] = sum_{j<=i} softmax_j( Kproj[i] . Qproj[j]*log2e/8 ) * V[j], exp2 domain.
// Block = 128 thr = 2 waves over the SAME 32 output rows; wave w processes
// j-tiles of parity w (flash-decoding split), one LDS combine at the end.
// S^T = mfma(K, Q): lane (hi,il) holds S[j=qj(r)][i=il]; P in registers (T12).
__global__ __launch_bounds__(128, 4) void attn_kernel(
    const u16* __restrict__ qarr, const u16* __restrict__ karr,
    const u16* __restrict__ vtarr, u16* __restrict__ aout,
    const int* __restrict__ cmask)
{
  __shared__ float cO[32 * 64];                 // wave1 partial O
  __shared__ float cm0[32], cl0[32], cm1[32], cl1[32];
  const int tid = threadIdx.x, lane = tid & 63, w = tid >> 6;
  const int il = lane & 31, hi = lane >> 5;
  const int bh = blockIdx.x;                    // bh -> XCD (K/Q/VT L2-resident)
  const int jw = 63 - (int)blockIdx.y;          // 32-row stripe, heavy first
  const int iw = jw * 32;
  const u16* Qh  = karr  + (size_t)bh * 131072; // output rows come from k-proj
  const u16* Kh  = qarr  + (size_t)bh * 131072; // keys are q-proj (pre-scaled)
  const u16* VTh = vtarr + (size_t)bh * 131072; // V transposed [d][s]
  const bool do_mask = (cmask[0] != 0);

  // persistent Q B-frags: bq[kt] holds Q[iw+il][kt*16 + 8*hi + e]
  bfrag bq[4];
  #pragma unroll
  for (int kt = 0; kt < 4; ++kt)
    bq[kt] = *(const bfrag*)(Qh + (size_t)(iw + il) * 64 + kt * 16 + hi * 8);

  f16x o0, o1;
  #pragma unroll
  for (int r = 0; r < 16; ++r){ o0[r] = 0.f; o1[r] = 0.f; }
  float m_s = -1e30f, l_s = 0.f;

  const int my_diag = do_mask ? (jw >> 1) : 31; // last 64-wide j-tile
  const int dsub    = jw & 1;                   // diagonal 32-subtile within it

  for (int jt = w; jt <= my_diag; jt += 2){     // parity split across the 2 waves
    const bool diag = do_mask && (jt == my_diag);
    const int nsub = diag ? (dsub + 1) : 2;     // wave-uniform
    const u16* Kt = Kh + (size_t)jt * 4096;

    // S^T = K . Q^T  (up to two 32x32 j-subtiles; K frags straight from L2)
    f16x s[2];
    #pragma unroll
    for (int sub = 0; sub < 2; ++sub)
      #pragma unroll
      for (int r = 0; r < 16; ++r) s[sub][r] = 0.f;
    __builtin_amdgcn_s_setprio(1);
    #pragma unroll
    for (int kt = 0; kt < 4; ++kt){
      #pragma unroll
      for (int sub = 0; sub < 2; ++sub){
        if (sub < nsub){
          bfrag ak = *(const bfrag*)(Kt + (size_t)(sub * 32 + il) * 64 + kt * 16 + hi * 8);
          s[sub] = __builtin_amdgcn_mfma_f32_32x32x16_bf16(ak, bq[kt], s[sub], 0, 0, 0);
        }
      }
    }
    __builtin_amdgcn_s_setprio(0);

    if (diag){                                  // mask j > i within the 32x32 diagonal
      #pragma unroll
      for (int r = 0; r < 16; ++r){
        const int qj = (r & 3) + 8 * (r >> 2) + 4 * hi;
        if (qj > il) s[dsub][r] = -1e30f;
      }
    }

    // row max: pairwise tree + 1 permlane32_swap
    float tmax = -1e30f;
    #pragma unroll
    for (int sub = 0; sub < 2; ++sub){
      if (sub < nsub){
        float a[8];
        #pragma unroll
        for (int e = 0; e < 8; ++e) a[e] = fmaxf(s[sub][e], s[sub][e + 8]);
        #pragma unroll
        for (int e = 0; e < 4; ++e) a[e] = fmaxf(a[e], a[e + 4]);
        a[0] = fmaxf(fmaxf(a[0], a[2]), fmaxf(a[1], a[3]));
        tmax = fmaxf(tmax, a[0]);
      }
    }
    {
      auto tt = __builtin_amdgcn_permlane32_swap(__float_as_uint(tmax),
                                                 __float_as_uint(tmax), false, false);
      tmax = fmaxf(__uint_as_float(tt[0]), __uint_as_float(tt[1]));
    }
    if (__any(tmax - m_s > 8.0f)){              // defer-max (THR=8)
      const float nm = fmaxf(m_s, tmax);
      const float sc = __builtin_amdgcn_exp2f(m_s - nm);
      m_s = nm; l_s *= sc;
      #pragma unroll
      for (int r = 0; r < 16; ++r){
        const float scb = __shfl(sc, (r & 3) + 8 * (r >> 2) + 4 * hi, 64);
        o0[r] *= scb; o1[r] *= scb;
      }
    }

    // P = exp2(S - m); scalar l (per-lane row sum + permlane); T12 P-frags -> PV
    float rsum = 0.f;
    #pragma unroll
    for (int sub = 0; sub < 2; ++sub){
      if (sub < nsub){
        #pragma unroll
        for (int r = 0; r < 16; ++r){
          s[sub][r] = __builtin_amdgcn_exp2f(s[sub][r] - m_s);
        }
        float a[8];
        #pragma unroll
        for (int e = 0; e < 8; ++e) a[e] = s[sub][e] + s[sub][e + 8];
        #pragma unroll
        for (int e = 0; e < 4; ++e) a[e] = a[e] + a[e + 4];
        rsum += (a[0] + a[2]) + (a[1] + a[3]);
      }
    }
    {
      auto rr = __builtin_amdgcn_permlane32_swap(__float_as_uint(rsum),
                                                 __float_as_uint(rsum), false, false);
      rsum = __uint_as_float(rr[0]) + __uint_as_float(rr[1]);
    }
    l_s += rsum;

    #pragma unroll
    for (int sub = 0; sub < 2; ++sub){
      if (sub < nsub){
        #pragma unroll
        for (int half = 0; half < 2; ++half){
          const int q0 = 8 * half;
          unsigned a0 = cvt_pk_bf16(s[sub][q0],     s[sub][q0 + 1]);
          unsigned a1 = cvt_pk_bf16(s[sub][q0 + 2], s[sub][q0 + 3]);
          unsigned b0 = cvt_pk_bf16(s[sub][q0 + 4], s[sub][q0 + 5]);
          unsigned b1 = cvt_pk_bf16(s[sub][q0 + 6], s[sub][q0 + 7]);
          auto r0p = __builtin_amdgcn_permlane32_swap(a0, b0, false, false);
          auto r1p = __builtin_amdgcn_permlane32_swap(a1, b1, false, false);
          union { bfrag f; unsigned u[4]; } pa;
          pa.u[0] = r0p[0]; pa.u[1] = r1p[0]; pa.u[2] = r0p[1]; pa.u[3] = r1p[1];

          const int jcol = jt * 64 + sub * 32 + half * 16 + hi * 8;
          bfrag v0 = *(const bfrag*)(VTh + (size_t)il * 2048 + jcol);
          bfrag v1 = *(const bfrag*)(VTh + (size_t)(32 + il) * 2048 + jcol);
          __builtin_amdgcn_s_setprio(1);
          o0 = __builtin_amdgcn_mfma_f32_32x32x16_bf16(pa.f, v0, o0, 0, 0, 0);
          o1 = __builtin_amdgcn_mfma_f32_32x32x16_bf16(pa.f, v1, o1, 0, 0, 0);
          __builtin_amdgcn_s_setprio(0);
        }
      }
    }
  }

  // ---- combine the two j-parity partials (R7-verified merge math) ----
  if (w == 1){
    #pragma unroll
    for (int r = 0; r < 16; ++r){
      const int row = (r & 3) + 8 * (r >> 2) + 4 * hi;
      cO[row * 64 + il]      = o0[r];
      cO[row * 64 + il + 32] = o1[r];
    }
    cm1[il] = m_s; cl1[il] = l_s;               // hi halves write same value
  } else {
    cm0[il] = m_s; cl0[il] = l_s;
  }
  __syncthreads();
  if (w == 0){
    const int bb = bh >> 4, h = bh & 15;
    #pragma unroll
    for (int r = 0; r < 16; ++r){
      const int rl = (r & 3) + 8 * (r >> 2) + 4 * hi;
      const float mA = cm0[rl], mB = cm1[rl];
      const float lA = cl0[rl], lB = cl1[rl];
      const float M  = fmaxf(mA, mB);
      const float eA = __builtin_amdgcn_exp2f(mA - M);
      const float eB = __builtin_amdgcn_exp2f(mB - M);
      const float inv = 1.0f / (lA * eA + lB * eB);
      const float ob0 = cO[rl * 64 + il], ob1 = cO[rl * 64 + il + 32];
      u16* dst = aout + (size_t)(bb * 2048 + iw + rl) * 1024 + h * 64 + il;
      dst[0]  = f2bf((o0[r] * eA + ob0 * eB) * inv);
      dst[32] = f2bf((o1[r] * eA + ob1 * eB) * inv);
    }
  }
}

// ---------------- launch ----------------
extern "C" void kernel_launch(void* const* d_in, const int* in_sizes, int n_in,
                              void* d_out, int out_size, void* d_ws, size_t ws_size,
                              hipStream_t stream)
{
  const float* x     = (const float*)d_in[0];
  const float* w_in  = (const float*)d_in[1];
  const float* b_in  = (const float*)d_in[2];
  const float* w_out = (const float*)d_in[3];
  const float* b_out = (const float*)d_in[4];
  const int*   cmask = (const int*)d_in[5];

  u16* ws     = (u16*)d_ws;
  u16* xb     = ws;                 // 4096x1024
  u16* winb   = ws + 4194304;       // 3072x1024
  u16* woutb  = ws + 7340032;       // 1024x1024
  u16* qs     = ws + 8388608;       // q,k: [2,16,2048,64]; VT: [2,16,64,2048]
  u16* attn_o = ws + 20971520;      // 4096x1024

  cvt_kernel<<<4096, 256, 0, stream>>>(x, xb, 4194304);
  cvt_kernel<<<3072, 256, 0, stream>>>(w_in, winb, 3145728);
  cvt_kernel<<<1024, 256, 0, stream>>>(w_out, woutb, 1048576);

  gemm_bt<1><<<dim3(24, 32), 256, 0, stream>>>(xb, winb, b_in, nullptr, qs, 4096, 3072, 1024);

  attn_kernel<<<dim3(32, 64), 128, 0, stream>>>(qs, qs + 4194304, qs + 8388608, attn_o, cmask);

  gemm_bt<0><<<dim3(8, 32), 256, 0, stream>>>(attn_o, woutb, b_out, (float*)d_out, nullptr,
                                              4096, 1024, 1024);
}

// Round 12
// 151.069 us; speedup vs baseline: 1.1202x; 1.0272x over previous
//
#include <hip/hip_runtime.h>

typedef unsigned short u16;
typedef short bfrag __attribute__((ext_vector_type(8)));   // 8 x bf16 (4 VGPRs)
typedef float facc  __attribute__((ext_vector_type(4)));   // 4 x f32
typedef float f16x  __attribute__((ext_vector_type(16)));  // 16 x f32 (32x32 acc)

__device__ __forceinline__ u16 f2bf(float f){
  union { float f; unsigned u; } v; v.f = f;
  unsigned r = v.u + 0x7fffu + ((v.u >> 16) & 1u);
  return (u16)(r >> 16);
}

__device__ __forceinline__ unsigned cvt_pk_bf16(float lo, float hi){
  unsigned d;
  asm("v_cvt_pk_bf16_f32 %0, %1, %2" : "=v"(d) : "v"(lo), "v"(hi));
  return d;
}

__device__ __forceinline__ void gl_lds16(const void* g, void* l){
  __builtin_amdgcn_global_load_lds(
      (const __attribute__((address_space(1))) unsigned int*)g,
      (__attribute__((address_space(3))) unsigned int*)l,
      16, 0, 0);
}

// ---------------- fp32 -> bf16 conversion ----------------
__global__ __launch_bounds__(256) void cvt_kernel(const float* __restrict__ src,
                                                  u16* __restrict__ dst, int n){
  int i = (blockIdx.x * 256 + threadIdx.x) * 4;
  if (i < n){
    float4 f = *(const float4*)(src + i);
    ushort4 o;
    o.x = f2bf(f.x); o.y = f2bf(f.y); o.z = f2bf(f.z); o.w = f2bf(f.w);
    *(ushort4*)(dst + i) = o;
  }
}

// ---------------- bf16 GEMM: C[m,n] = sum_k A[m,k]*B[n,k] + bias[n] ----------------
__device__ __forceinline__ void stage_tile(const u16* __restrict__ G, u16* lds,
                                           int row0, int k0, int K, int tid){
  #pragma unroll
  for (int c = 0; c < 2; ++c){
    int e = c * 2048 + tid * 8;
    int row = e >> 5, col = e & 31;
    gl_lds16(G + (size_t)(row0 + row) * K + k0 + col, lds + c * 2048 + (tid >> 6) * 512);
  }
}

template<int EPI>
__global__ __launch_bounds__(256) void gemm_bt(
    const u16* __restrict__ A, const u16* __restrict__ B,
    const float* __restrict__ bias, float* __restrict__ Cf,
    u16* __restrict__ qkv, int M, int N, int K)
{
  __shared__ u16 Ash[2][4096];
  __shared__ u16 Bsh[2][4096];
  const int tid = threadIdx.x, lane = tid & 63;
  const int w = tid >> 6, wm = w >> 1, wn = w & 1;
  const int cl = lane & 15, g8 = (lane >> 4) * 8;
  const int n0 = blockIdx.x * 128, m0 = blockIdx.y * 128;

  facc acc[4][4];
  #pragma unroll
  for (int mi = 0; mi < 4; ++mi)
    #pragma unroll
    for (int ni = 0; ni < 4; ++ni)
      acc[mi][ni] = (facc){0.f, 0.f, 0.f, 0.f};

  const int NT = K >> 5;
  stage_tile(A, Ash[0], m0, 0, K, tid);
  stage_tile(B, Bsh[0], n0, 0, K, tid);
  __syncthreads();
  int cur = 0;
  for (int kt = 0; kt < NT; ++kt){
    if (kt + 1 < NT){
      stage_tile(A, Ash[cur ^ 1], m0, (kt + 1) << 5, K, tid);
      stage_tile(B, Bsh[cur ^ 1], n0, (kt + 1) << 5, K, tid);
    }
    const u16* As = Ash[cur]; const u16* Bs = Bsh[cur];
    bfrag af[4], bfr[4];
    #pragma unroll
    for (int mi = 0; mi < 4; ++mi)
      af[mi] = *(const bfrag*)&As[(wm * 64 + mi * 16 + cl) * 32 + g8];
    #pragma unroll
    for (int ni = 0; ni < 4; ++ni)
      bfr[ni] = *(const bfrag*)&Bs[(wn * 64 + ni * 16 + cl) * 32 + g8];
    #pragma unroll
    for (int mi = 0; mi < 4; ++mi)
      #pragma unroll
      for (int ni = 0; ni < 4; ++ni)
        acc[mi][ni] = __builtin_amdgcn_mfma_f32_16x16x32_bf16(af[mi], bfr[ni], acc[mi][ni], 0, 0, 0);
    __syncthreads();
    cur ^= 1;
  }

  const int r0 = (lane >> 4) * 4;
  #pragma unroll
  for (int mi = 0; mi < 4; ++mi){
    const int mbase = m0 + wm * 64 + mi * 16 + r0;
    #pragma unroll
    for (int ni = 0; ni < 4; ++ni){
      const int n = n0 + wn * 64 + ni * 16 + cl;
      const float bv = bias[n];
      #pragma unroll
      for (int j = 0; j < 4; ++j){
        float v = acc[mi][ni][j] + bv;
        const int mm = mbase + j;
        if (EPI == 0){
          Cf[(size_t)mm * N + n] = v;
        } else {
          const int part = n >> 10, rest = n & 1023;
          const int h = rest >> 6, d = rest & 63;
          const int bb = mm >> 11, s = mm & 2047;
          // fold 1/sqrt(dh)=1/8 AND log2(e) into q so attention uses exp2 directly
          if (part == 0) v *= 0.18033688011112042f;
          if (part < 2){
            qkv[(size_t)part * 4194304 + (size_t)((bb * 16 + h) * 2048 + s) * 64 + d] = f2bf(v);
          } else {
            // v stored TRANSPOSED: VT[bh][d][s] so attention reads contiguous j-runs
            qkv[(size_t)2 * 4194304 + (size_t)((bb * 16 + h) * 64 + d) * 2048 + s] = f2bf(v);
          }
        }
      }
    }
  }
}

// ---------------- swapped-role causal flash attention (LDS-free core) ----------
// out[i] = sum_{j<=i} softmax_j( Kproj[i] . Qproj[j]*log2e/8 ) * V[j], exp2 domain.
// Block = 128 thr = 2 waves over the SAME 32 output rows; wave w processes
// j-tiles of parity w (flash-decoding split), one LDS combine at the end.
// All 16 operand loads per iteration issued up-front (wide liveness -> MLP).
__global__ __launch_bounds__(128, 3) void attn_kernel(
    const u16* __restrict__ qarr, const u16* __restrict__ karr,
    const u16* __restrict__ vtarr, u16* __restrict__ aout,
    const int* __restrict__ cmask)
{
  __shared__ float cO[32 * 64];                 // wave1 partial O
  __shared__ float cm0[32], cl0[32], cm1[32], cl1[32];
  const int tid = threadIdx.x, lane = tid & 63, w = tid >> 6;
  const int il = lane & 31, hi = lane >> 5;
  const int bh = blockIdx.x;                    // bh -> XCD (K/Q/VT L2-resident)
  const int jw = 63 - (int)blockIdx.y;          // 32-row stripe, heavy first
  const int iw = jw * 32;
  const u16* Qh  = karr  + (size_t)bh * 131072; // output rows come from k-proj
  const u16* Kh  = qarr  + (size_t)bh * 131072; // keys are q-proj (pre-scaled)
  const u16* VTh = vtarr + (size_t)bh * 131072; // V transposed [d][s]
  const bool do_mask = (cmask[0] != 0);

  // persistent Q B-frags: bq[kt] holds Q[iw+il][kt*16 + 8*hi + e]
  bfrag bq[4];
  #pragma unroll
  for (int kt = 0; kt < 4; ++kt)
    bq[kt] = *(const bfrag*)(Qh + (size_t)(iw + il) * 64 + kt * 16 + hi * 8);

  f16x o0, o1;
  #pragma unroll
  for (int r = 0; r < 16; ++r){ o0[r] = 0.f; o1[r] = 0.f; }
  float m_s = -1e30f, l_s = 0.f;

  const int my_diag = do_mask ? (jw >> 1) : 31; // last 64-wide j-tile
  const int dsub    = jw & 1;                   // diagonal 32-subtile within it

  for (int jt = w; jt <= my_diag; jt += 2){     // parity split across the 2 waves
    const bool diag = do_mask && (jt == my_diag);
    const int nsub = diag ? (dsub + 1) : 2;     // wave-uniform
    const u16* Kt = Kh + (size_t)jt * 4096;

    // issue ALL 16 independent loads first: V (used last) then K (used next)
    bfrag vf[8];                                // vf[half*4 + ...]: V^T frags
    #pragma unroll
    for (int half = 0; half < 2; ++half){
      const int jcol = jt * 64 + half * 16 + hi * 8;   // sub=0 cols
      vf[half * 2 + 0] = *(const bfrag*)(VTh + (size_t)il * 2048 + jcol);
      vf[half * 2 + 1] = *(const bfrag*)(VTh + (size_t)(32 + il) * 2048 + jcol);
      vf[4 + half * 2 + 0] = *(const bfrag*)(VTh + (size_t)il * 2048 + jcol + 32);
      vf[4 + half * 2 + 1] = *(const bfrag*)(VTh + (size_t)(32 + il) * 2048 + jcol + 32);
    }
    bfrag kf[8];                                // kf[sub*4 + kt]
    #pragma unroll
    for (int kt = 0; kt < 4; ++kt){
      kf[kt]     = *(const bfrag*)(Kt + (size_t)il * 64 + kt * 16 + hi * 8);
      kf[4 + kt] = *(const bfrag*)(Kt + (size_t)(32 + il) * 64 + kt * 16 + hi * 8);
    }

    // S^T = K . Q^T  (up to two 32x32 j-subtiles)
    f16x s[2];
    #pragma unroll
    for (int sub = 0; sub < 2; ++sub)
      #pragma unroll
      for (int r = 0; r < 16; ++r) s[sub][r] = 0.f;
    __builtin_amdgcn_s_setprio(1);
    #pragma unroll
    for (int kt = 0; kt < 4; ++kt){
      s[0] = __builtin_amdgcn_mfma_f32_32x32x16_bf16(kf[kt], bq[kt], s[0], 0, 0, 0);
      if (nsub > 1)
        s[1] = __builtin_amdgcn_mfma_f32_32x32x16_bf16(kf[4 + kt], bq[kt], s[1], 0, 0, 0);
    }
    __builtin_amdgcn_s_setprio(0);

    if (diag){                                  // mask j > i within the 32x32 diagonal
      #pragma unroll
      for (int r = 0; r < 16; ++r){
        const int qj = (r & 3) + 8 * (r >> 2) + 4 * hi;
        if (qj > il) s[dsub][r] = -1e30f;
      }
    }

    // row max: pairwise tree + 1 permlane32_swap
    float tmax = -1e30f;
    #pragma unroll
    for (int sub = 0; sub < 2; ++sub){
      if (sub < nsub){
        float a[8];
        #pragma unroll
        for (int e = 0; e < 8; ++e) a[e] = fmaxf(s[sub][e], s[sub][e + 8]);
        #pragma unroll
        for (int e = 0; e < 4; ++e) a[e] = fmaxf(a[e], a[e + 4]);
        a[0] = fmaxf(fmaxf(a[0], a[2]), fmaxf(a[1], a[3]));
        tmax = fmaxf(tmax, a[0]);
      }
    }
    {
      auto tt = __builtin_amdgcn_permlane32_swap(__float_as_uint(tmax),
                                                 __float_as_uint(tmax), false, false);
      tmax = fmaxf(__uint_as_float(tt[0]), __uint_as_float(tt[1]));
    }
    if (__any(tmax - m_s > 8.0f)){              // defer-max (THR=8)
      const float nm = fmaxf(m_s, tmax);
      const float sc = __builtin_amdgcn_exp2f(m_s - nm);
      m_s = nm; l_s *= sc;
      #pragma unroll
      for (int r = 0; r < 16; ++r){
        const float scb = __shfl(sc, (r & 3) + 8 * (r >> 2) + 4 * hi, 64);
        o0[r] *= scb; o1[r] *= scb;
      }
    }

    // P = exp2(S - m); scalar l (per-lane row sum + permlane)
    float rsum = 0.f;
    #pragma unroll
    for (int sub = 0; sub < 2; ++sub){
      if (sub < nsub){
        #pragma unroll
        for (int r = 0; r < 16; ++r)
          s[sub][r] = __builtin_amdgcn_exp2f(s[sub][r] - m_s);
        float a[8];
        #pragma unroll
        for (int e = 0; e < 8; ++e) a[e] = s[sub][e] + s[sub][e + 8];
        #pragma unroll
        for (int e = 0; e < 4; ++e) a[e] = a[e] + a[e + 4];
        rsum += (a[0] + a[2]) + (a[1] + a[3]);
      }
    }
    {
      auto rr = __builtin_amdgcn_permlane32_swap(__float_as_uint(rsum),
                                                 __float_as_uint(rsum), false, false);
      rsum = __uint_as_float(rr[0]) + __uint_as_float(rr[1]);
    }
    l_s += rsum;

    // T12: cvt_pk + permlane32_swap -> PV A-frags; PV with prefetched vf
    #pragma unroll
    for (int sub = 0; sub < 2; ++sub){
      if (sub < nsub){
        #pragma unroll
        for (int half = 0; half < 2; ++half){
          const int q0 = 8 * half;
          unsigned a0 = cvt_pk_bf16(s[sub][q0],     s[sub][q0 + 1]);
          unsigned a1 = cvt_pk_bf16(s[sub][q0 + 2], s[sub][q0 + 3]);
          unsigned b0 = cvt_pk_bf16(s[sub][q0 + 4], s[sub][q0 + 5]);
          unsigned b1 = cvt_pk_bf16(s[sub][q0 + 6], s[sub][q0 + 7]);
          auto r0p = __builtin_amdgcn_permlane32_swap(a0, b0, false, false);
          auto r1p = __builtin_amdgcn_permlane32_swap(a1, b1, false, false);
          union { bfrag f; unsigned u[4]; } pa;
          pa.u[0] = r0p[0]; pa.u[1] = r1p[0]; pa.u[2] = r0p[1]; pa.u[3] = r1p[1];

          __builtin_amdgcn_s_setprio(1);
          o0 = __builtin_amdgcn_mfma_f32_32x32x16_bf16(pa.f, vf[sub * 4 + half * 2 + 0], o0, 0, 0, 0);
          o1 = __builtin_amdgcn_mfma_f32_32x32x16_bf16(pa.f, vf[sub * 4 + half * 2 + 1], o1, 0, 0, 0);
          __builtin_amdgcn_s_setprio(0);
        }
      }
    }
  }

  // ---- combine the two j-parity partials (verified merge math) ----
  if (w == 1){
    #pragma unroll
    for (int r = 0; r < 16; ++r){
      const int row = (r & 3) + 8 * (r >> 2) + 4 * hi;
      cO[row * 64 + il]      = o0[r];
      cO[row * 64 + il + 32] = o1[r];
    }
    cm1[il] = m_s; cl1[il] = l_s;               // hi halves write same value
  } else {
    cm0[il] = m_s; cl0[il] = l_s;
  }
  __syncthreads();
  if (w == 0){
    const int bb = bh >> 4, h = bh & 15;
    #pragma unroll
    for (int r = 0; r < 16; ++r){
      const int rl = (r & 3) + 8 * (r >> 2) + 4 * hi;
      const float mA = cm0[rl], mB = cm1[rl];
      const float lA = cl0[rl], lB = cl1[rl];
      const float M  = fmaxf(mA, mB);
      const float eA = __builtin_amdgcn_exp2f(mA - M);
      const float eB = __builtin_amdgcn_exp2f(mB - M);
      const float inv = 1.0f / (lA * eA + lB * eB);
      const float ob0 = cO[rl * 64 + il], ob1 = cO[rl * 64 + il + 32];
      u16* dst = aout + (size_t)(bb * 2048 + iw + rl) * 1024 + h * 64 + il;
      dst[0]  = f2bf((o0[r] * eA + ob0 * eB) * inv);
      dst[32] = f2bf((o1[r] * eA + ob1 * eB) * inv);
    }
  }
}

// ---------------- launch ----------------
extern "C" void kernel_launch(void* const* d_in, const int* in_sizes, int n_in,
                              void* d_out, int out_size, void* d_ws, size_t ws_size,
                              hipStream_t stream)
{
  const float* x     = (const float*)d_in[0];
  const float* w_in  = (const float*)d_in[1];
  const float* b_in  = (const float*)d_in[2];
  const float* w_out = (const float*)d_in[3];
  const float* b_out = (const float*)d_in[4];
  const int*   cmask = (const int*)d_in[5];

  u16* ws     = (u16*)d_ws;
  u16* xb     = ws;                 // 4096x1024
  u16* winb   = ws + 4194304;       // 3072x1024
  u16* woutb  = ws + 7340032;       // 1024x1024
  u16* qs     = ws + 8388608;       // q,k: [2,16,2048,64]; VT: [2,16,64,2048]
  u16* attn_o = ws + 20971520;      // 4096x1024

  cvt_kernel<<<4096, 256, 0, stream>>>(x, xb, 4194304);
  cvt_kernel<<<3072, 256, 0, stream>>>(w_in, winb, 3145728);
  cvt_kernel<<<1024, 256, 0, stream>>>(w_out, woutb, 1048576);

  gemm_bt<1><<<dim3(24, 32), 256, 0, stream>>>(xb, winb, b_in, nullptr, qs, 4096, 3072, 1024);

  attn_kernel<<<dim3(32, 64), 128, 0, stream>>>(qs, qs + 4194304, qs + 8388608, attn_o, cmask);

  gemm_bt<0><<<dim3(8, 32), 256, 0, stream>>>(attn_o, woutb, b_out, (float*)d_out, nullptr,
                                              4096, 1024, 1024);
}

// Round 14
// 148.020 us; speedup vs baseline: 1.1432x; 1.0206x over previous
//
#include <hip/hip_runtime.h>

typedef unsigned short u16;
typedef short bfrag __attribute__((ext_vector_type(8)));   // 8 x bf16 (4 VGPRs)
typedef float facc  __attribute__((ext_vector_type(4)));   // 4 x f32
typedef float f16x  __attribute__((ext_vector_type(16)));  // 16 x f32 (32x32 acc)

__device__ __forceinline__ u16 f2bf(float f){
  union { float f; unsigned u; } v; v.f = f;
  unsigned r = v.u + 0x7fffu + ((v.u >> 16) & 1u);
  return (u16)(r >> 16);
}

__device__ __forceinline__ unsigned cvt_pk_bf16(float lo, float hi){
  unsigned d;
  asm("v_cvt_pk_bf16_f32 %0, %1, %2" : "=v"(d) : "v"(lo), "v"(hi));
  return d;
}

__device__ __forceinline__ void gl_lds16(const void* g, void* l){
  __builtin_amdgcn_global_load_lds(
      (const __attribute__((address_space(1))) unsigned int*)g,
      (__attribute__((address_space(3))) unsigned int*)l,
      16, 0, 0);
}

// ---------------- fused fp32 -> bf16 conversion (3 tensors, 1 launch) ----------
__global__ __launch_bounds__(256) void cvt3_kernel(
    const float* __restrict__ s0, u16* __restrict__ d0, int n0,   // x
    const float* __restrict__ s1, u16* __restrict__ d1, int n1,   // w_in
    const float* __restrict__ s2, u16* __restrict__ d2)           // w_out
{
  int i = (blockIdx.x * 256 + threadIdx.x) * 4;
  const float* src; u16* dst;
  if (i < n0){ src = s0; dst = d0; }
  else if (i < n0 + n1){ src = s1; dst = d1; i -= n0; }
  else { src = s2; dst = d2; i -= n0 + n1; }
  float4 f = *(const float4*)(src + i);
  ushort4 o;
  o.x = f2bf(f.x); o.y = f2bf(f.y); o.z = f2bf(f.z); o.w = f2bf(f.w);
  *(ushort4*)(dst + i) = o;
}

// ---------------- bf16 GEMM: C[m,n] = sum_k A[m,k]*B[n,k] + bias[n] ----------------
__device__ __forceinline__ void stage_tile(const u16* __restrict__ G, u16* lds,
                                           int row0, int k0, int K, int tid){
  #pragma unroll
  for (int c = 0; c < 2; ++c){
    int e = c * 2048 + tid * 8;
    int row = e >> 5, col = e & 31;
    gl_lds16(G + (size_t)(row0 + row) * K + k0 + col, lds + c * 2048 + (tid >> 6) * 512);
  }
}

template<int EPI>
__global__ __launch_bounds__(256) void gemm_bt(
    const u16* __restrict__ A, const u16* __restrict__ B,
    const float* __restrict__ bias, float* __restrict__ Cf,
    u16* __restrict__ qkv, int M, int N, int K)
{
  __shared__ u16 smem[16384];                   // staging; reused as transpose buf
  u16* Ash = smem;                              // [2][4096]
  u16* Bsh = smem + 8192;                       // [2][4096]
  const int tid = threadIdx.x, lane = tid & 63;
  const int w = tid >> 6, wm = w >> 1, wn = w & 1;
  const int cl = lane & 15, g8 = (lane >> 4) * 8;
  const int n0 = blockIdx.x * 128, m0 = blockIdx.y * 128;

  facc acc[4][4];
  #pragma unroll
  for (int mi = 0; mi < 4; ++mi)
    #pragma unroll
    for (int ni = 0; ni < 4; ++ni)
      acc[mi][ni] = (facc){0.f, 0.f, 0.f, 0.f};

  const int NT = K >> 5;
  stage_tile(A, Ash, m0, 0, K, tid);
  stage_tile(B, Bsh, n0, 0, K, tid);
  __syncthreads();
  int cur = 0;
  for (int kt = 0; kt < NT; ++kt){
    if (kt + 1 < NT){
      stage_tile(A, Ash + (cur ^ 1) * 4096, m0, (kt + 1) << 5, K, tid);
      stage_tile(B, Bsh + (cur ^ 1) * 4096, n0, (kt + 1) << 5, K, tid);
    }
    const u16* As = Ash + cur * 4096; const u16* Bs = Bsh + cur * 4096;
    bfrag af[4], bfr[4];
    #pragma unroll
    for (int mi = 0; mi < 4; ++mi)
      af[mi] = *(const bfrag*)&As[(wm * 64 + mi * 16 + cl) * 32 + g8];
    #pragma unroll
    for (int ni = 0; ni < 4; ++ni)
      bfr[ni] = *(const bfrag*)&Bs[(wn * 64 + ni * 16 + cl) * 32 + g8];
    #pragma unroll
    for (int mi = 0; mi < 4; ++mi)
      #pragma unroll
      for (int ni = 0; ni < 4; ++ni)
        acc[mi][ni] = __builtin_amdgcn_mfma_f32_16x16x32_bf16(af[mi], bfr[ni], acc[mi][ni], 0, 0, 0);
    __syncthreads();
    cur ^= 1;
  }

  const int r0 = (lane >> 4) * 4;
  const bool isv = (EPI == 1) && (n0 >= 2048);  // whole block is the v-part

  if (!isv){
    #pragma unroll
    for (int mi = 0; mi < 4; ++mi){
      const int mbase = m0 + wm * 64 + mi * 16 + r0;
      #pragma unroll
      for (int ni = 0; ni < 4; ++ni){
        const int n = n0 + wn * 64 + ni * 16 + cl;
        const float bv = bias[n];
        #pragma unroll
        for (int j = 0; j < 4; ++j){
          float v = acc[mi][ni][j] + bv;
          const int mm = mbase + j;
          if (EPI == 0){
            Cf[(size_t)mm * N + n] = v;
          } else {
            const int part = n >> 10, rest = n & 1023;
            const int h = rest >> 6, d = rest & 63;
            const int bb = mm >> 11, s = mm & 2047;
            // fold 1/sqrt(dh)=1/8 AND log2(e) into q: attention uses exp2 directly
            if (part == 0) v *= 0.18033688011112042f;
            qkv[(size_t)part * 4194304 + (size_t)((bb * 16 + h) * 2048 + s) * 64 + d] = f2bf(v);
          }
        }
      }
    }
  } else {
    // v-part: transpose through LDS -> coalesced VT[bh][d][s] stores
    u16* tr = smem;                             // [64][132] bf16 (staging is dead)
    const int bb = m0 >> 11;
    const int s0 = m0 & 2047;                   // sequence base within the batch
    const int h0 = (n0 - 2048) >> 6;
    u16* vt_base = qkv + (size_t)2 * 4194304;
    const int trow = tid >> 2, tq = tid & 3;    // readout coords
    #pragma unroll
    for (int p = 0; p < 2; ++p){
      __syncthreads();                          // tr free (prev pass done / loop done)
      if (wn == p){
        #pragma unroll
        for (int mi = 0; mi < 4; ++mi){
          const int sl = wm * 64 + mi * 16 + r0;
          #pragma unroll
          for (int ni = 0; ni < 4; ++ni){
            const int i = ni * 16 + cl;         // d
            const float bv = bias[n0 + p * 64 + i];
            #pragma unroll
            for (int j = 0; j < 4; ++j)
              tr[i * 132 + sl + j] = f2bf(acc[mi][ni][j] + bv);
          }
        }
      }
      __syncthreads();
      // stream out: 256 threads, 64 d-rows, each thread 32 contiguous u16 = 64B
      u16* dst = vt_base + (size_t)((bb * 16 + h0 + p) * 64 + trow) * 2048 + s0 + tq * 32;
      const u16* srcr = tr + trow * 132 + tq * 32;
      #pragma unroll
      for (int k = 0; k < 4; ++k)
        *(uint4*)(dst + k * 8) = *(const uint4*)(srcr + k * 8);
    }
  }
}

// ---------------- swapped-role causal flash attention (LDS-free core) ----------
// out[i] = sum_{j<=i} softmax_j( Kproj[i] . Qproj[j]*log2e/8 ) * V[j], exp2 domain.
// Block = 128 thr = 2 waves over the SAME 32 output rows; wave w processes
// j-tiles of parity w (flash-decoding split), one LDS combine at the end.
__global__ __launch_bounds__(128, 3) void attn_kernel(
    const u16* __restrict__ qarr, const u16* __restrict__ karr,
    const u16* __restrict__ vtarr, u16* __restrict__ aout,
    const int* __restrict__ cmask)
{
  __shared__ float cO[32 * 64];                 // wave1 partial O
  __shared__ float cm0[32], cl0[32], cm1[32], cl1[32];
  const int tid = threadIdx.x, lane = tid & 63, w = tid >> 6;
  const int il = lane & 31, hi = lane >> 5;
  const int bh = blockIdx.x;                    // bh -> XCD (K/Q/VT L2-resident)
  const int jw = 63 - (int)blockIdx.y;          // 32-row stripe, heavy first
  const int iw = jw * 32;
  const u16* Qh  = karr  + (size_t)bh * 131072; // output rows come from k-proj
  const u16* Kh  = qarr  + (size_t)bh * 131072; // keys are q-proj (pre-scaled)
  const u16* VTh = vtarr + (size_t)bh * 131072; // V transposed [d][s]
  const bool do_mask = (cmask[0] != 0);

  // persistent Q B-frags: bq[kt] holds Q[iw+il][kt*16 + 8*hi + e]
  bfrag bq[4];
  #pragma unroll
  for (int kt = 0; kt < 4; ++kt)
    bq[kt] = *(const bfrag*)(Qh + (size_t)(iw + il) * 64 + kt * 16 + hi * 8);

  f16x o0, o1;
  #pragma unroll
  for (int r = 0; r < 16; ++r){ o0[r] = 0.f; o1[r] = 0.f; }
  float m_s = -1e30f, l_s = 0.f;

  const int my_diag = do_mask ? (jw >> 1) : 31; // last 64-wide j-tile
  const int dsub    = jw & 1;                   // diagonal 32-subtile within it

  for (int jt = w; jt <= my_diag; jt += 2){     // parity split across the 2 waves
    const bool diag = do_mask && (jt == my_diag);
    const int nsub = diag ? (dsub + 1) : 2;     // wave-uniform
    const u16* Kt = Kh + (size_t)jt * 4096;

    // issue ALL 16 independent loads first: V (used last) then K (used next)
    bfrag vf[8];
    #pragma unroll
    for (int half = 0; half < 2; ++half){
      const int jcol = jt * 64 + half * 16 + hi * 8;
      vf[half * 2 + 0] = *(const bfrag*)(VTh + (size_t)il * 2048 + jcol);
      vf[half * 2 + 1] = *(const bfrag*)(VTh + (size_t)(32 + il) * 2048 + jcol);
      vf[4 + half * 2 + 0] = *(const bfrag*)(VTh + (size_t)il * 2048 + jcol + 32);
      vf[4 + half * 2 + 1] = *(const bfrag*)(VTh + (size_t)(32 + il) * 2048 + jcol + 32);
    }
    bfrag kf[8];
    #pragma unroll
    for (int kt = 0; kt < 4; ++kt){
      kf[kt]     = *(const bfrag*)(Kt + (size_t)il * 64 + kt * 16 + hi * 8);
      kf[4 + kt] = *(const bfrag*)(Kt + (size_t)(32 + il) * 64 + kt * 16 + hi * 8);
    }

    // S^T = K . Q^T  (up to two 32x32 j-subtiles)
    f16x s[2];
    #pragma unroll
    for (int sub = 0; sub < 2; ++sub)
      #pragma unroll
      for (int r = 0; r < 16; ++r) s[sub][r] = 0.f;
    __builtin_amdgcn_s_setprio(1);
    #pragma unroll
    for (int kt = 0; kt < 4; ++kt){
      s[0] = __builtin_amdgcn_mfma_f32_32x32x16_bf16(kf[kt], bq[kt], s[0], 0, 0, 0);
      if (nsub > 1)
        s[1] = __builtin_amdgcn_mfma_f32_32x32x16_bf16(kf[4 + kt], bq[kt], s[1], 0, 0, 0);
    }
    __builtin_amdgcn_s_setprio(0);

    if (diag){                                  // mask j > i within the 32x32 diagonal
      #pragma unroll
      for (int r = 0; r < 16; ++r){
        const int qj = (r & 3) + 8 * (r >> 2) + 4 * hi;
        if (qj > il) s[dsub][r] = -1e30f;
      }
    }

    // row max: pairwise tree + 1 permlane32_swap
    float tmax = -1e30f;
    #pragma unroll
    for (int sub = 0; sub < 2; ++sub){
      if (sub < nsub){
        float a[8];
        #pragma unroll
        for (int e = 0; e < 8; ++e) a[e] = fmaxf(s[sub][e], s[sub][e + 8]);
        #pragma unroll
        for (int e = 0; e < 4; ++e) a[e] = fmaxf(a[e], a[e + 4]);
        a[0] = fmaxf(fmaxf(a[0], a[2]), fmaxf(a[1], a[3]));
        tmax = fmaxf(tmax, a[0]);
      }
    }
    {
      auto tt = __builtin_amdgcn_permlane32_swap(__float_as_uint(tmax),
                                                 __float_as_uint(tmax), false, false);
      tmax = fmaxf(__uint_as_float(tt[0]), __uint_as_float(tt[1]));
    }
    if (__any(tmax - m_s > 8.0f)){              // defer-max (THR=8)
      const float nm = fmaxf(m_s, tmax);
      const float sc = __builtin_amdgcn_exp2f(m_s - nm);
      m_s = nm; l_s *= sc;
      #pragma unroll
      for (int r = 0; r < 16; ++r){
        const float scb = __shfl(sc, (r & 3) + 8 * (r >> 2) + 4 * hi, 64);
        o0[r] *= scb; o1[r] *= scb;
      }
    }

    // P = exp2(S - m); scalar l (per-lane row sum + permlane)
    float rsum = 0.f;
    #pragma unroll
    for (int sub = 0; sub < 2; ++sub){
      if (sub < nsub){
        #pragma unroll
        for (int r = 0; r < 16; ++r)
          s[sub][r] = __builtin_amdgcn_exp2f(s[sub][r] - m_s);
        float a[8];
        #pragma unroll
        for (int e = 0; e < 8; ++e) a[e] = s[sub][e] + s[sub][e + 8];
        #pragma unroll
        for (int e = 0; e < 4; ++e) a[e] = a[e] + a[e + 4];
        rsum += (a[0] + a[2]) + (a[1] + a[3]);
      }
    }
    {
      auto rr = __builtin_amdgcn_permlane32_swap(__float_as_uint(rsum),
                                                 __float_as_uint(rsum), false, false);
      rsum = __uint_as_float(rr[0]) + __uint_as_float(rr[1]);
    }
    l_s += rsum;

    // T12: cvt_pk + permlane32_swap -> PV A-frags; PV with prefetched vf
    #pragma unroll
    for (int sub = 0; sub < 2; ++sub){
      if (sub < nsub){
        #pragma unroll
        for (int half = 0; half < 2; ++half){
          const int q0 = 8 * half;
          unsigned a0 = cvt_pk_bf16(s[sub][q0],     s[sub][q0 + 1]);
          unsigned a1 = cvt_pk_bf16(s[sub][q0 + 2], s[sub][q0 + 3]);
          unsigned b0 = cvt_pk_bf16(s[sub][q0 + 4], s[sub][q0 + 5]);
          unsigned b1 = cvt_pk_bf16(s[sub][q0 + 6], s[sub][q0 + 7]);
          auto r0p = __builtin_amdgcn_permlane32_swap(a0, b0, false, false);
          auto r1p = __builtin_amdgcn_permlane32_swap(a1, b1, false, false);
          union { bfrag f; unsigned u[4]; } pa;
          pa.u[0] = r0p[0]; pa.u[1] = r1p[0]; pa.u[2] = r0p[1]; pa.u[3] = r1p[1];

          __builtin_amdgcn_s_setprio(1);
          o0 = __builtin_amdgcn_mfma_f32_32x32x16_bf16(pa.f, vf[sub * 4 + half * 2 + 0], o0, 0, 0, 0);
          o1 = __builtin_amdgcn_mfma_f32_32x32x16_bf16(pa.f, vf[sub * 4 + half * 2 + 1], o1, 0, 0, 0);
          __builtin_amdgcn_s_setprio(0);
        }
      }
    }
  }

  // ---- combine the two j-parity partials (verified merge math) ----
  if (w == 1){
    #pragma unroll
    for (int r = 0; r < 16; ++r){
      const int row = (r & 3) + 8 * (r >> 2) + 4 * hi;
      cO[row * 64 + il]      = o0[r];
      cO[row * 64 + il + 32] = o1[r];
    }
    cm1[il] = m_s; cl1[il] = l_s;
  } else {
    cm0[il] = m_s; cl0[il] = l_s;
  }
  __syncthreads();
  if (w == 0){
    const int bb = bh >> 4, h = bh & 15;
    #pragma unroll
    for (int r = 0; r < 16; ++r){
      const int rl = (r & 3) + 8 * (r >> 2) + 4 * hi;
      const float mA = cm0[rl], mB = cm1[rl];
      const float lA = cl0[rl], lB = cl1[rl];
      const float M  = fmaxf(mA, mB);
      const float eA = __builtin_amdgcn_exp2f(mA - M);
      const float eB = __builtin_amdgcn_exp2f(mB - M);
      const float inv = 1.0f / (lA * eA + lB * eB);
      const float ob0 = cO[rl * 64 + il], ob1 = cO[rl * 64 + il + 32];
      u16* dst = aout + (size_t)(bb * 2048 + iw + rl) * 1024 + h * 64 + il;
      dst[0]  = f2bf((o0[r] * eA + ob0 * eB) * inv);
      dst[32] = f2bf((o1[r] * eA + ob1 * eB) * inv);
    }
  }
}

// ---------------- launch ----------------
extern "C" void kernel_launch(void* const* d_in, const int* in_sizes, int n_in,
                              void* d_out, int out_size, void* d_ws, size_t ws_size,
                              hipStream_t stream)
{
  const float* x     = (const float*)d_in[0];
  const float* w_in  = (const float*)d_in[1];
  const float* b_in  = (const float*)d_in[2];
  const float* w_out = (const float*)d_in[3];
  const float* b_out = (const float*)d_in[4];
  const int*   cmask = (const int*)d_in[5];

  u16* ws     = (u16*)d_ws;
  u16* xb     = ws;                 // 4096x1024
  u16* winb   = ws + 4194304;       // 3072x1024
  u16* woutb  = ws + 7340032;       // 1024x1024
  u16* qs     = ws + 8388608;       // q,k: [2,16,2048,64]; VT: [2,16,64,2048]
  u16* attn_o = ws + 20971520;      // 4096x1024

  cvt3_kernel<<<8192, 256, 0, stream>>>(x, xb, 4194304,
                                        w_in, winb, 3145728,
                                        w_out, woutb);

  gemm_bt<1><<<dim3(24, 32), 256, 0, stream>>>(xb, winb, b_in, nullptr, qs, 4096, 3072, 1024);

  attn_kernel<<<dim3(32, 64), 128, 0, stream>>>(qs, qs + 4194304, qs + 8388608, attn_o, cmask);

  gemm_bt<0><<<dim3(8, 32), 256, 0, stream>>>(attn_o, woutb, b_out, (float*)d_out, nullptr,
                                              4096, 1024, 1024);
}